// Round 9
// baseline (2379.142 us; speedup 1.0000x reference)
//
#include <hip/hip_runtime.h>

#define LL 256
#define DD 512

typedef _Float16 f16;
typedef _Float16 f16x4_t __attribute__((ext_vector_type(4)));
typedef _Float16 f16x8_t __attribute__((ext_vector_type(8)));
typedef float f32x4_t __attribute__((ext_vector_type(4)));

__device__ __forceinline__ f16x8_t cvt2(const float4 a, const float4 b) {
  f16x8_t v;
  v[0] = (f16)a.x; v[1] = (f16)a.y; v[2] = (f16)a.z; v[3] = (f16)a.w;
  v[4] = (f16)b.x; v[5] = (f16)b.y; v[6] = (f16)b.z; v[7] = (f16)b.w;
  return v;
}

// ---------------- prep: Wt[e][d] = (f16) W[d][e] ----------------
__global__ void k_prep(const float* __restrict__ W, f16* __restrict__ Wt) {
  __shared__ float t[64][65];
  int bx = blockIdx.x & 7;   // e tile
  int by = blockIdx.x >> 3;  // d tile
  int tx = threadIdx.x & 63, tg = threadIdx.x >> 6;
  for (int r = tg; r < 64; r += 4)
    t[r][tx] = W[(by * 64 + r) * DD + bx * 64 + tx];
  __syncthreads();
  for (int r = tg; r < 64; r += 4)
    Wt[(bx * 64 + r) * DD + by * 64 + tx] = (f16)t[tx][r];
}

// LDS R1 (128KB), time-shared:
//   quarter loop: P_q[64 l][512 e] f16 @0 (64KB, XOR-baked rows 1KB)
//                 y dbuf 2x[256 m][64 e] f16 @65536,98304 (baked rows 128B)
//   after: A_w[256 l][256 m] f16 (rows 512B, baked)
// LDS R2 (16KB): phase0 x dbuf 2x[64 l][64 d] f16 (2x8KB); phase B YT; then gp/beta

__global__ __launch_bounds__(512, 2)
void k_main(const float* __restrict__ gi, const float* __restrict__ gj,
            const f16* __restrict__ Wt, const float* __restrict__ wv,
            f16* __restrict__ slabs, float* __restrict__ out) {
  __shared__ __align__(16) char R1[131072];
  __shared__ __align__(16) char R2[16384];

  const int tid = threadIdx.x;
  const int lane = tid & 63;
  const int wave = tid >> 6;  // 0..7
  const int lq = lane & 15, lg = lane >> 4;

  const int sb = blockIdx.x;
  const int wk = (sb & 7) * 128 + (sb >> 3);  // XCD swizzle (bijective, 1024%8==0)
  const int b = wk >> 1, side = wk & 1;
  const float* __restrict__ x = (side ? gj : gi) + (size_t)b * (LL * DD);
  const float* __restrict__ y = (side ? gi : gj) + (size_t)b * (LL * DD);
  f16* __restrict__ slab = slabs + (size_t)wk * (LL * DD);  // only a[l][d]

  char* const R1c = R1;
  char* const R2c = R2;

  // S accumulators: m = wave*32 + mf*16 + lg*4 + r ; l = nfg*16 + lq
  f32x4_t accS[2][16];
#pragma unroll
  for (int mf = 0; mf < 2; ++mf)
#pragma unroll
    for (int nfg = 0; nfg < 16; ++nfg) accS[mf][nfg] = (f32x4_t){0.f, 0.f, 0.f, 0.f};

  const int wvl = wave & 1, wve = wave >> 1;  // phase0: l-sub(2x32), e-sub(4x64)
  const int xrow = tid >> 3, xsl = tid & 7;   // x stage: 64 rows x 8 slots(16B)
  const int prow = tid >> 1, phalf = tid & 1; // y stage: 256 rows x 2 halves(64B)

#pragma unroll
  for (int q = 0; q < 4; ++q) {
    // ========== phase 0 quarter: P_q = x[q*64..+64][:] @ W -> R1[0,64K) ==========
#pragma unroll
    for (int eh = 0; eh < 2; ++eh) {
      f32x4_t acc[4][2];  // [ef][lf]: e = eh*256+wve*64+ef*16+lg*4+r ; l = wvl*32+lf*16+lq
#pragma unroll
      for (int ef = 0; ef < 4; ++ef)
#pragma unroll
        for (int lf = 0; lf < 2; ++lf) acc[ef][lf] = (f32x4_t){0.f, 0.f, 0.f, 0.f};

      {  // stage x s=0 into R2 buf0
        const float* src = x + (size_t)(q * 64 + xrow) * DD + xsl * 8;
        float4 a0 = *(const float4*)src, a1 = *(const float4*)(src + 4);
        *(f16x8_t*)(R2c + xrow * 128 + ((xsl * 16) ^ ((unsigned)(xrow & 7) << 4))) =
            cvt2(a0, a1);
      }
      __syncthreads();

      for (int s = 0; s < 8; ++s) {
        char* xc = R2c + (s & 1) * 8192;
        char* xn = R2c + ((s + 1) & 1) * 8192;
        float4 p0, p1;
        if (s < 7) {
          const float* src = x + (size_t)(q * 64 + xrow) * DD + (s + 1) * 64 + xsl * 8;
          p0 = *(const float4*)src; p1 = *(const float4*)(src + 4);
        }
#pragma unroll
        for (int ks = 0; ks < 2; ++ks) {
          f16x8_t aF[4], bF[2];
#pragma unroll
          for (int ef = 0; ef < 4; ++ef) {
            int e = eh * 256 + wve * 64 + ef * 16 + lq;
            aF[ef] = *(const f16x8_t*)(Wt + (size_t)e * DD + s * 64 + ks * 32 + lg * 8);
          }
#pragma unroll
          for (int lf = 0; lf < 2; ++lf) {
            int l = wvl * 32 + lf * 16 + lq;
            bF[lf] = *(const f16x8_t*)(xc + l * 128 +
                       ((ks * 64 + lg * 16) ^ ((unsigned)(l & 7) << 4)));
          }
#pragma unroll
          for (int ef = 0; ef < 4; ++ef)
#pragma unroll
            for (int lf = 0; lf < 2; ++lf)
              acc[ef][lf] = __builtin_amdgcn_mfma_f32_16x16x32_f16(aF[ef], bF[lf], acc[ef][lf], 0, 0, 0);
        }
        if (s < 7) {
          *(f16x8_t*)(xn + xrow * 128 + ((xsl * 16) ^ ((unsigned)(xrow & 7) << 4))) =
              cvt2(p0, p1);
        }
        __syncthreads();
      }
      // writeback P_q e-half: f16x4 along e, baked within 128B chunk
#pragma unroll
      for (int ef = 0; ef < 4; ++ef)
#pragma unroll
        for (int lf = 0; lf < 2; ++lf) {
          int l_loc = wvl * 32 + lf * 16 + lq;
          int e0 = eh * 256 + wve * 64 + ef * 16 + lg * 4;
          f16x4_t v;
          v[0] = (f16)acc[ef][lf][0]; v[1] = (f16)acc[ef][lf][1];
          v[2] = (f16)acc[ef][lf][2]; v[3] = (f16)acc[ef][lf][3];
          *(f16x4_t*)(R1c + l_loc * 1024 + (e0 >> 6) * 128 +
                      (((unsigned)((e0 & 63) * 2)) ^ ((unsigned)(l_loc & 7) << 4))) = v;
        }
    }
    __syncthreads();  // P_q complete & visible

    // ========== phase A quarter: accS[:, q*4..+4] += y @ P_q^T ==========
    {  // stage y s=0 into R1+65536 buf0
      const float* src = y + (size_t)prow * DD + phalf * 32;
      unsigned bk = (unsigned)(prow & 7) << 4;
#pragma unroll
      for (int u = 0; u < 4; ++u) {
        float4 a0 = *(const float4*)(src + u * 8);
        float4 a1 = *(const float4*)(src + u * 8 + 4);
        *(f16x8_t*)(R1c + 65536 + prow * 128 + ((phalf * 64 + u * 16) ^ bk)) = cvt2(a0, a1);
      }
    }
    __syncthreads();

    for (int s = 0; s < 8; ++s) {
      const char* Yc = R1c + 65536 + (s & 1) * 32768;
      float4 pre_y[8];
      if (s < 7) {
        const float* src = y + (size_t)prow * DD + (s + 1) * 64 + phalf * 32;
#pragma unroll
        for (int u = 0; u < 8; ++u) pre_y[u] = *(const float4*)(src + u * 4);
      }
#pragma unroll
      for (int ks = 0; ks < 2; ++ks) {
        f16x8_t aF[2], bF[4];
#pragma unroll
        for (int mf = 0; mf < 2; ++mf) {
          int m = wave * 32 + mf * 16 + lq;
          aF[mf] = *(const f16x8_t*)(Yc + m * 128 +
                     ((ks * 64 + lg * 16) ^ ((unsigned)(m & 7) << 4)));
        }
#pragma unroll
        for (int nf = 0; nf < 4; ++nf) {
          int l_loc = nf * 16 + lq;
          bF[nf] = *(const f16x8_t*)(R1c + l_loc * 1024 + s * 128 +
                     ((ks * 64 + lg * 16) ^ ((unsigned)(l_loc & 7) << 4)));
        }
#pragma unroll
        for (int mf = 0; mf < 2; ++mf)
#pragma unroll
          for (int nf = 0; nf < 4; ++nf)
            accS[mf][q * 4 + nf] =
                __builtin_amdgcn_mfma_f32_16x16x32_f16(aF[mf], bF[nf], accS[mf][q * 4 + nf], 0, 0, 0);
      }
      if (s < 7) {
        char* Yn = R1c + 65536 + ((s + 1) & 1) * 32768;
        unsigned bk = (unsigned)(prow & 7) << 4;
#pragma unroll
        for (int u = 0; u < 4; ++u)
          *(f16x8_t*)(Yn + prow * 128 + ((phalf * 64 + u * 16) ^ bk)) =
              cvt2(pre_y[2 * u], pre_y[2 * u + 1]);
      }
      __syncthreads();
    }
  }  // q

  // ========== softmax over l — fully in-wave (wave owns m = wave*32..+32) ==========
  float inv_[2][4];
#pragma unroll
  for (int mf = 0; mf < 2; ++mf)
#pragma unroll
    for (int r = 0; r < 4; ++r) {
      float v = accS[mf][0][r];
#pragma unroll
      for (int nfg = 1; nfg < 16; ++nfg) v = fmaxf(v, accS[mf][nfg][r]);
      v = fmaxf(v, __shfl_xor(v, 1));
      v = fmaxf(v, __shfl_xor(v, 2));
      v = fmaxf(v, __shfl_xor(v, 4));
      v = fmaxf(v, __shfl_xor(v, 8));
      float ss = 0.f;
#pragma unroll
      for (int nfg = 0; nfg < 16; ++nfg) {
        float p = __expf(accS[mf][nfg][r] - v);
        accS[mf][nfg][r] = p;
        ss += p;
      }
      ss += __shfl_xor(ss, 1);
      ss += __shfl_xor(ss, 2);
      ss += __shfl_xor(ss, 4);
      ss += __shfl_xor(ss, 8);
      inv_[mf][r] = 1.f / ss;
    }

  // A_w[256 l][256 m] writeback into R1 (P_q/y bufs dead since last barrier)
#pragma unroll
  for (int mf = 0; mf < 2; ++mf)
#pragma unroll
    for (int nfg = 0; nfg < 16; ++nfg) {
      int l = nfg * 16 + lq;
      int m0 = wave * 32 + mf * 16 + lg * 4;
      f16x4_t v;
      v[0] = (f16)(accS[mf][nfg][0] * inv_[mf][0]);
      v[1] = (f16)(accS[mf][nfg][1] * inv_[mf][1]);
      v[2] = (f16)(accS[mf][nfg][2] * inv_[mf][2]);
      v[3] = (f16)(accS[mf][nfg][3] * inv_[mf][3]);
      *(f16x4_t*)(R1c + l * 512 +
                  (((unsigned)(m0 * 2)) ^ ((unsigned)(l & 7) << 4))) = v;
    }
  __syncthreads();

  // ========== phase B: a = A_w @ y ; fused g partials ; dense a[l][d] -> slab ==========
  float* const gp    = (float*)R2c;           // [2][256] (after YT dead)
  float* const betas = (float*)(R2c + 2048);
  {
    const int wl3 = wave & 3, wd = wave >> 2;
    float garr[4][4];
#pragma unroll
    for (int lf = 0; lf < 4; ++lf)
#pragma unroll
      for (int r = 0; r < 4; ++r) garr[lf][r] = 0.f;

    const int yd = tid & 127, ymq = tid >> 7;
    f16* const a_ = slab;

    for (int dct = 0; dct < 4; ++dct) {
      f32x4_t accB[4][4];  // [lf][df]
#pragma unroll
      for (int lf = 0; lf < 4; ++lf)
#pragma unroll
        for (int df = 0; df < 4; ++df) accB[lf][df] = (f32x4_t){0.f, 0.f, 0.f, 0.f};

      float lyA[4][4], lyB[4][4];
#pragma unroll
      for (int u = 0; u < 4; ++u) {
        int m0 = ymq * 16 + u * 4;
#pragma unroll
        for (int k = 0; k < 4; ++k)
          lyA[u][k] = y[(size_t)(m0 + k) * DD + dct * 128 + yd];
      }
#pragma unroll
      for (int mh = 0; mh < 4; ++mh) {
        __syncthreads();  // prev YT reads done
        {
          unsigned swz = (unsigned)(yd & 7) << 4;
#pragma unroll
          for (int u = 0; u < 4; ++u) {
            int m0 = ymq * 16 + u * 4;
            f16x4_t v;
            if (mh & 1) {
              v[0] = (f16)lyB[u][0]; v[1] = (f16)lyB[u][1];
              v[2] = (f16)lyB[u][2]; v[3] = (f16)lyB[u][3];
            } else {
              v[0] = (f16)lyA[u][0]; v[1] = (f16)lyA[u][1];
              v[2] = (f16)lyA[u][2]; v[3] = (f16)lyA[u][3];
            }
            *(f16x4_t*)(R2c + yd * 128 + ((m0 * 2) ^ swz)) = v;
          }
        }
        __syncthreads();
        if (mh < 3) {  // prefetch next mh (hidden under MFMA)
#pragma unroll
          for (int u = 0; u < 4; ++u) {
            int m0 = (mh + 1) * 64 + ymq * 16 + u * 4;
#pragma unroll
            for (int k = 0; k < 4; ++k) {
              float lv = y[(size_t)(m0 + k) * DD + dct * 128 + yd];
              if (mh & 1) lyA[u][k] = lv; else lyB[u][k] = lv;
            }
          }
        }
#pragma unroll
        for (int ks = 0; ks < 2; ++ks) {
          f16x8_t aF[4], bF[4];
#pragma unroll
          for (int lf = 0; lf < 4; ++lf) {
            int row = wl3 * 64 + lf * 16 + lq;
            aF[lf] = *(const f16x8_t*)(R1c + row * 512 +
                       ((mh * 128 + ks * 64 + lg * 16) ^ ((unsigned)(row & 7) << 4)));
          }
#pragma unroll
          for (int df = 0; df < 4; ++df) {
            int row = wd * 64 + df * 16 + lq;
            bF[df] = *(const f16x8_t*)(R2c + row * 128 +
                       ((ks * 64 + lg * 16) ^ ((unsigned)(row & 7) << 4)));
          }
#pragma unroll
          for (int lf = 0; lf < 4; ++lf)
#pragma unroll
            for (int df = 0; df < 4; ++df)
              accB[lf][df] = __builtin_amdgcn_mfma_f32_16x16x32_f16(aF[lf], bF[df], accB[lf][df], 0, 0, 0);
        }
      }
      // epilogue: g partials + dense a[l][d] writes
      float wvA[4], wvB[4];
#pragma unroll
      for (int df = 0; df < 4; ++df) {
        int d = dct * 128 + wd * 64 + df * 16 + lq;
        wvA[df] = wv[d];
        wvB[df] = wv[DD + d];
      }
#pragma unroll
      for (int lf = 0; lf < 4; ++lf)
#pragma unroll
        for (int r = 0; r < 4; ++r) {
          int l = wl3 * 64 + lf * 16 + lg * 4 + r;
          float gs = 0.f;
#pragma unroll
          for (int df = 0; df < 4; ++df) {
            int d = dct * 128 + wd * 64 + df * 16 + lq;
            float av = accB[lf][df][r];
            float xv = x[(size_t)l * DD + d];
            gs += (xv - av) * wvA[df] + (xv * av) * wvB[df];
            a_[(size_t)l * DD + d] = (f16)av;
          }
          gs += __shfl_xor(gs, 1);
          gs += __shfl_xor(gs, 2);
          gs += __shfl_xor(gs, 4);
          gs += __shfl_xor(gs, 8);
          garr[lf][r] += gs;
        }
    }
    __syncthreads();  // YT dead -> R2 becomes gp/beta
    if (lq == 0) {
#pragma unroll
      for (int lf = 0; lf < 4; ++lf)
#pragma unroll
        for (int r = 0; r < 4; ++r)
          gp[wd * 256 + wl3 * 64 + lf * 16 + lg * 4 + r] = garr[lf][r];
    }
  }
  __threadfence_block();
  __syncthreads();

  // ========== beta = softmax_l(g) (wave 0) ==========
  if (wave == 0) {
    float gv[4];
    float M = -3.4e38f;
#pragma unroll
    for (int u = 0; u < 4; ++u) {
      int l = lane + u * 64;
      gv[u] = gp[l] + gp[256 + l];
      M = fmaxf(M, gv[u]);
    }
#pragma unroll
    for (int s = 1; s < 64; s <<= 1) M = fmaxf(M, __shfl_xor(M, s));
    float S = 0.f, ev[4];
#pragma unroll
    for (int u = 0; u < 4; ++u) { ev[u] = __expf(gv[u] - M); S += ev[u]; }
#pragma unroll
    for (int s = 1; s < 64; s <<= 1) S += __shfl_xor(S, s);
    float inv = 1.f / S;
#pragma unroll
    for (int u = 0; u < 4; ++u) betas[lane + u * 64] = ev[u] * inv;
  }
  __syncthreads();

  // ========== pooled output: coalesced a[l][d] + x[l][d] reads ==========
  {
    const f16* const a_ = slab;
    int dc = tid;
    float s1 = 0.f, s2 = 0.f;
    for (int l = 0; l < 256; ++l) {
      float bl = betas[l];
      float av = (float)a_[(size_t)l * DD + dc];
      float xv = x[(size_t)l * DD + dc];
      s1 += bl * (xv - av);
      s2 += bl * (xv * av);
    }
    size_t o = (size_t)side * (512u * 1024u) + (size_t)b * 1024u;
    out[o + dc] = s1;
    out[o + DD + dc] = s2;
  }
}

extern "C" void kernel_launch(void* const* d_in, const int* in_sizes, int n_in,
                              void* d_out, int out_size, void* d_ws, size_t ws_size,
                              hipStream_t stream) {
  (void)in_sizes; (void)n_in; (void)out_size; (void)ws_size;
  const float* gi = (const float*)d_in[0];
  const float* gj = (const float*)d_in[1];
  const float* W  = (const float*)d_in[2];
  const float* wv = (const float*)d_in[3];
  float* out = (float*)d_out;
  f16* Wt = (f16*)d_ws;                 // 512x512 f16 = 512 KiB
  f16* slabs = Wt + DD * DD;            // 1024 slabs x 256 KiB (a[l][d] only)
  k_prep<<<dim3(64), dim3(256), 0, stream>>>(W, Wt);
  k_main<<<dim3(1024), dim3(512), 0, stream>>>(gi, gj, Wt, wv, slabs, out);
}

// Round 11
// 1047.286 us; speedup vs baseline: 2.2717x; 2.2717x over previous
//
#include <hip/hip_runtime.h>

#define LL 256
#define DD 512

typedef _Float16 f16;
typedef _Float16 f16x4_t __attribute__((ext_vector_type(4)));
typedef _Float16 f16x8_t __attribute__((ext_vector_type(8)));
typedef float f32x4_t __attribute__((ext_vector_type(4)));

__device__ __forceinline__ f16x8_t cvt2(const float4 a, const float4 b) {
  f16x8_t v;
  v[0] = (f16)a.x; v[1] = (f16)a.y; v[2] = (f16)a.z; v[3] = (f16)a.w;
  v[4] = (f16)b.x; v[5] = (f16)b.y; v[6] = (f16)b.z; v[7] = (f16)b.w;
  return v;
}

// ---------------- prep: Wt[e][d] = (f16) W[d][e] ----------------
__global__ void k_prep(const float* __restrict__ W, f16* __restrict__ Wt) {
  __shared__ float t[64][65];
  int bx = blockIdx.x & 7;   // e tile
  int by = blockIdx.x >> 3;  // d tile
  int tx = threadIdx.x & 63, tg = threadIdx.x >> 6;
  for (int r = tg; r < 64; r += 4)
    t[r][tx] = W[(by * 64 + r) * DD + bx * 64 + tx];
  __syncthreads();
  for (int r = tg; r < 64; r += 4)
    Wt[(bx * 64 + r) * DD + by * 64 + tx] = (f16)t[tx][r];
}

// LDS:
//  R1 128KB: phase0 x dbuf 2x16KB -> A_w[256 l][256 m] f16 (rows 512B, XOR-baked)
//  R2 16KB : phase A softmax colred/colmax/colinv ; phase B YT[128 d][64 m] f16
//  R3 8KB  : gp[2][256] @0 ; betas[256] @2048 ; s1dct[4][128] @3072 ; s2dct[4][128] @5120

__global__ __launch_bounds__(512, 2)
void k_main(const float* __restrict__ gi, const float* __restrict__ gj,
            const f16* __restrict__ Wt, const float* __restrict__ wv,
            f16* __restrict__ slabs, float* __restrict__ out) {
  __shared__ __align__(16) char R1[131072];
  __shared__ __align__(16) char R2[16384];
  __shared__ __align__(16) char R3[8192];

  const int tid = threadIdx.x;
  const int lane = tid & 63;
  const int wave = tid >> 6;  // 0..7
  const int lq = lane & 15, lg = lane >> 4;

  const int sb = blockIdx.x;
  const int wk = (sb & 7) * 128 + (sb >> 3);  // XCD swizzle (bijective, 1024%8==0)
  const int b = wk >> 1, side = wk & 1;
  const float* __restrict__ x = (side ? gj : gi) + (size_t)b * (LL * DD);
  const float* __restrict__ y = (side ? gi : gj) + (size_t)b * (LL * DD);
  f16* __restrict__ slab = slabs + (size_t)wk * (LL * DD);  // P only (baked rows)

  char* const R1c = R1;
  char* const R2c = R2;
  float* const colred = (float*)R2c;            // [2][256]
  float* const colmax = (float*)(R2c + 2048);
  float* const colinv = (float*)(R2c + 3072);
  float* const gp     = (float*)R3;             // [2][256]
  float* const betas  = (float*)(R3 + 2048);    // [256]
  float* const s1dct  = (float*)(R3 + 3072);    // [4][128]
  float* const s2dct  = (float*)(R3 + 5120);    // [4][128]

  // ============ phase 0: P = x @ W -> slab (f16, per-128B-chunk XOR-baked) ============
  // mfma(A = x rows l, B = Wt rows e): acc(l = reg, e = lq)
  {
    const int wl2 = wave & 1, we4 = wave >> 1;
    for (int lh = 0; lh < 2; ++lh) {
      f32x4_t acc[4][8];  // [lf][ef]
#pragma unroll
      for (int lf = 0; lf < 4; ++lf)
#pragma unroll
        for (int ef = 0; ef < 8; ++ef) acc[lf][ef] = (f32x4_t){0.f, 0.f, 0.f, 0.f};

      const int xrow = tid >> 2;
      const int xc4 = (tid & 3) * 16;
      {
        const float* src = x + (size_t)(lh * 128 + xrow) * DD + xc4;
        float4 a0 = *(const float4*)src, a1 = *(const float4*)(src + 4);
        float4 a2 = *(const float4*)(src + 8), a3 = *(const float4*)(src + 12);
        unsigned swz = (unsigned)(xrow & 7) << 4;
        *(f16x8_t*)(R1c + xrow * 128 + ((xc4 * 2) ^ swz)) = cvt2(a0, a1);
        *(f16x8_t*)(R1c + xrow * 128 + ((xc4 * 2 + 16) ^ swz)) = cvt2(a2, a3);
      }
      __syncthreads();

      for (int s = 0; s < 8; ++s) {
        char* xbc = R1c + (s & 1) * 16384;
        char* xbn = R1c + ((s + 1) & 1) * 16384;
        float4 p0, p1, p2, p3;
        if (s < 7) {
          const float* src = x + (size_t)(lh * 128 + xrow) * DD + (s + 1) * 64 + xc4;
          p0 = *(const float4*)src; p1 = *(const float4*)(src + 4);
          p2 = *(const float4*)(src + 8); p3 = *(const float4*)(src + 12);
        }
#pragma unroll
        for (int ks = 0; ks < 2; ++ks) {
          f16x8_t aF[4], bF[8];
#pragma unroll
          for (int lf = 0; lf < 4; ++lf) {
            int row = wl2 * 64 + lf * 16 + lq;
            aF[lf] = *(const f16x8_t*)(xbc + row * 128 +
                       ((ks * 64 + lg * 16) ^ ((unsigned)(row & 7) << 4)));
          }
#pragma unroll
          for (int ef = 0; ef < 8; ++ef) {
            int er = we4 * 128 + ef * 16 + lq;
            bF[ef] = *(const f16x8_t*)(Wt + (size_t)er * DD + s * 64 + ks * 32 + lg * 8);
          }
#pragma unroll
          for (int lf = 0; lf < 4; ++lf)
#pragma unroll
            for (int ef = 0; ef < 8; ++ef)
              acc[lf][ef] = __builtin_amdgcn_mfma_f32_16x16x32_f16(aF[lf], bF[ef], acc[lf][ef], 0, 0, 0);
        }
        if (s < 7) {
          unsigned swz = (unsigned)(xrow & 7) << 4;
          *(f16x8_t*)(xbn + xrow * 128 + ((xc4 * 2) ^ swz)) = cvt2(p0, p1);
          *(f16x8_t*)(xbn + xrow * 128 + ((xc4 * 2 + 16) ^ swz)) = cvt2(p2, p3);
        }
        __syncthreads();
      }
      // writeback: dense scalar f16 (16 lanes = 32B contiguous), XOR baked per 128B chunk
#pragma unroll
      for (int lf = 0; lf < 4; ++lf)
#pragma unroll
        for (int ef = 0; ef < 8; ++ef) {
          int e = we4 * 128 + ef * 16 + lq;
          int l0 = lh * 128 + wl2 * 64 + lf * 16 + lg * 4;
#pragma unroll
          for (int r = 0; r < 4; ++r) {
            int l = l0 + r;
            size_t byte = (size_t)l * 1024 + (size_t)(e >> 6) * 128 +
                          (unsigned)(((e & 63) * 2) ^ ((l & 7) << 4));
            *(f16*)((char*)slab + byte) = (f16)acc[lf][ef][r];
          }
        }
    }
  }
  __threadfence_block();
  __syncthreads();

  // ============ phase A: St = y @ P^T, acc(m = reg, l = lq), S in regs ============
  // Barrier-free K-loop: P fragments and y fragments read DIRECTLY from global (L2-hot).
  {
    const int wm = wave & 3, wl = wave >> 2;
    f32x4_t accS[4][8];  // [mf][nf]
#pragma unroll
    for (int mf = 0; mf < 4; ++mf)
#pragma unroll
      for (int nf = 0; nf < 8; ++nf) accS[mf][nf] = (f32x4_t){0.f, 0.f, 0.f, 0.f};

#pragma unroll 2
    for (int s = 0; s < 8; ++s) {
#pragma unroll
      for (int ks = 0; ks < 2; ++ks) {
        f16x8_t aF[4], bF[8];
#pragma unroll
        for (int mf = 0; mf < 4; ++mf) {
          int m = wm * 64 + mf * 16 + lq;
          const float* src = y + (size_t)m * DD + s * 64 + ks * 32 + lg * 8;
          float4 a0 = *(const float4*)src, a1 = *(const float4*)(src + 4);
          aF[mf] = cvt2(a0, a1);
        }
#pragma unroll
        for (int nf = 0; nf < 8; ++nf) {
          int l = wl * 128 + nf * 16 + lq;
          bF[nf] = *(const f16x8_t*)((const char*)slab + (size_t)l * 1024 + s * 128 +
                     ((ks * 64 + lg * 16) ^ ((unsigned)(l & 7) << 4)));
        }
#pragma unroll
        for (int mf = 0; mf < 4; ++mf)
#pragma unroll
          for (int nf = 0; nf < 8; ++nf)
            accS[mf][nf] = __builtin_amdgcn_mfma_f32_16x16x32_f16(aF[mf], bF[nf], accS[mf][nf], 0, 0, 0);
      }
    }

    // ---- softmax over l (per column m) ----
    float red[4][4];
#pragma unroll
    for (int mf = 0; mf < 4; ++mf)
#pragma unroll
      for (int r = 0; r < 4; ++r) {
        float v = accS[mf][0][r];
#pragma unroll
        for (int nf = 1; nf < 8; ++nf) v = fmaxf(v, accS[mf][nf][r]);
        v = fmaxf(v, __shfl_xor(v, 1));
        v = fmaxf(v, __shfl_xor(v, 2));
        v = fmaxf(v, __shfl_xor(v, 4));
        v = fmaxf(v, __shfl_xor(v, 8));
        red[mf][r] = v;
      }
    if (lq == 0) {
#pragma unroll
      for (int mf = 0; mf < 4; ++mf)
#pragma unroll
        for (int r = 0; r < 4; ++r)
          colred[wl * 256 + wm * 64 + mf * 16 + lg * 4 + r] = red[mf][r];
    }
    __syncthreads();
    if (tid < 256) colmax[tid] = fmaxf(colred[tid], colred[256 + tid]);
    __syncthreads();
    float cm[4][4];
#pragma unroll
    for (int mf = 0; mf < 4; ++mf)
#pragma unroll
      for (int r = 0; r < 4; ++r) cm[mf][r] = colmax[wm * 64 + mf * 16 + lg * 4 + r];
    __syncthreads();
#pragma unroll
    for (int mf = 0; mf < 4; ++mf)
#pragma unroll
      for (int r = 0; r < 4; ++r) {
        float s = 0.f;
#pragma unroll
        for (int nf = 0; nf < 8; ++nf) {
          float p = __expf(accS[mf][nf][r] - cm[mf][r]);
          accS[mf][nf][r] = p;
          s += p;
        }
        s += __shfl_xor(s, 1);
        s += __shfl_xor(s, 2);
        s += __shfl_xor(s, 4);
        s += __shfl_xor(s, 8);
        red[mf][r] = s;
      }
    if (lq == 0) {
#pragma unroll
      for (int mf = 0; mf < 4; ++mf)
#pragma unroll
        for (int r = 0; r < 4; ++r)
          colred[wl * 256 + wm * 64 + mf * 16 + lg * 4 + r] = red[mf][r];
    }
    __syncthreads();
    if (tid < 256) colinv[tid] = 1.f / (colred[tid] + colred[256 + tid]);
    __syncthreads();
    float inv[4][4];
#pragma unroll
    for (int mf = 0; mf < 4; ++mf)
#pragma unroll
      for (int r = 0; r < 4; ++r) inv[mf][r] = colinv[wm * 64 + mf * 16 + lg * 4 + r];
    __syncthreads();  // all waves past phase 0 / softmax reads; R1 becomes A_w
#pragma unroll
    for (int mf = 0; mf < 4; ++mf)
#pragma unroll
      for (int nf = 0; nf < 8; ++nf) {
        int l = wl * 128 + nf * 16 + lq;
        f16x4_t v;
        v[0] = (f16)(accS[mf][nf][0] * inv[mf][0]);
        v[1] = (f16)(accS[mf][nf][1] * inv[mf][1]);
        v[2] = (f16)(accS[mf][nf][2] * inv[mf][2]);
        v[3] = (f16)(accS[mf][nf][3] * inv[mf][3]);
        *(f16x4_t*)(R1c + l * 512 +
                    ((wm * 128 + mf * 32 + lg * 8) ^ ((unsigned)(l & 7) << 4))) = v;
      }
  }
  __syncthreads();

  // ============ phase B: two passes over a = A_w @ y ============
  const int wl3 = wave & 3, wd = wave >> 2;
  const int yd = tid & 127, ymq = tid >> 7;

  // shared dct body: stages YT (R2), accumulates accB over m
  auto run_dct = [&](int dct, f32x4_t (&accB)[4][4]) {
    float lyA[4][4], lyB[4][4];
#pragma unroll
    for (int u = 0; u < 4; ++u) {
      int m0 = ymq * 16 + u * 4;
#pragma unroll
      for (int k = 0; k < 4; ++k)
        lyA[u][k] = y[(size_t)(m0 + k) * DD + dct * 128 + yd];
    }
#pragma unroll
    for (int mh = 0; mh < 4; ++mh) {
      __syncthreads();  // prev YT reads done
      {
        unsigned swz = (unsigned)(yd & 7) << 4;
#pragma unroll
        for (int u = 0; u < 4; ++u) {
          int m0 = ymq * 16 + u * 4;
          f16x4_t v;
          if (mh & 1) {
            v[0] = (f16)lyB[u][0]; v[1] = (f16)lyB[u][1];
            v[2] = (f16)lyB[u][2]; v[3] = (f16)lyB[u][3];
          } else {
            v[0] = (f16)lyA[u][0]; v[1] = (f16)lyA[u][1];
            v[2] = (f16)lyA[u][2]; v[3] = (f16)lyA[u][3];
          }
          *(f16x4_t*)(R2c + yd * 128 + ((m0 * 2) ^ swz)) = v;
        }
      }
      __syncthreads();
      if (mh < 3) {
#pragma unroll
        for (int u = 0; u < 4; ++u) {
          int m0 = (mh + 1) * 64 + ymq * 16 + u * 4;
#pragma unroll
          for (int k = 0; k < 4; ++k) {
            float lv = y[(size_t)(m0 + k) * DD + dct * 128 + yd];
            if (mh & 1) lyA[u][k] = lv; else lyB[u][k] = lv;
          }
        }
      }
#pragma unroll
      for (int ks = 0; ks < 2; ++ks) {
        f16x8_t aF[4], bF[4];
#pragma unroll
        for (int lf = 0; lf < 4; ++lf) {
          int row = wl3 * 64 + lf * 16 + lq;
          aF[lf] = *(const f16x8_t*)(R1c + row * 512 +
                     ((mh * 128 + ks * 64 + lg * 16) ^ ((unsigned)(row & 7) << 4)));
        }
#pragma unroll
        for (int df = 0; df < 4; ++df) {
          int row = wd * 64 + df * 16 + lq;
          bF[df] = *(const f16x8_t*)(R2c + row * 128 +
                     ((ks * 64 + lg * 16) ^ ((unsigned)(row & 7) << 4)));
        }
#pragma unroll
        for (int lf = 0; lf < 4; ++lf)
#pragma unroll
          for (int df = 0; df < 4; ++df)
            accB[lf][df] = __builtin_amdgcn_mfma_f32_16x16x32_f16(aF[lf], bF[df], accB[lf][df], 0, 0, 0);
      }
    }
  };

  // ---- pass 1: logits g ----
  {
    float garr[4][4];
#pragma unroll
    for (int lf = 0; lf < 4; ++lf)
#pragma unroll
      for (int r = 0; r < 4; ++r) garr[lf][r] = 0.f;

    for (int dct = 0; dct < 4; ++dct) {
      f32x4_t accB[4][4];
#pragma unroll
      for (int lf = 0; lf < 4; ++lf)
#pragma unroll
        for (int df = 0; df < 4; ++df) accB[lf][df] = (f32x4_t){0.f, 0.f, 0.f, 0.f};
      run_dct(dct, accB);

      float wvA[4], wvB[4];
#pragma unroll
      for (int df = 0; df < 4; ++df) {
        int d = dct * 128 + wd * 64 + df * 16 + lq;
        wvA[df] = wv[d];
        wvB[df] = wv[DD + d];
      }
#pragma unroll
      for (int lf = 0; lf < 4; ++lf)
#pragma unroll
        for (int r = 0; r < 4; ++r) {
          int l = wl3 * 64 + lf * 16 + lg * 4 + r;
          float gs = 0.f;
#pragma unroll
          for (int df = 0; df < 4; ++df) {
            int d = dct * 128 + wd * 64 + df * 16 + lq;
            float av = accB[lf][df][r];
            float xv = x[(size_t)l * DD + d];
            gs += (xv - av) * wvA[df] + (xv * av) * wvB[df];
          }
          gs += __shfl_xor(gs, 1);
          gs += __shfl_xor(gs, 2);
          gs += __shfl_xor(gs, 4);
          gs += __shfl_xor(gs, 8);
          garr[lf][r] += gs;
        }
    }
    __syncthreads();  // YT reads of last dct done (for safety before gp reuse patterns)
    if (lq == 0) {
#pragma unroll
      for (int lf = 0; lf < 4; ++lf)
#pragma unroll
        for (int r = 0; r < 4; ++r)
          gp[wd * 256 + wl3 * 64 + lf * 16 + lg * 4 + r] = garr[lf][r];
    }
  }
  __syncthreads();

  // ---- beta = softmax_l(g) (wave 0) ----
  if (wave == 0) {
    float gv[4];
    float M = -3.4e38f;
#pragma unroll
    for (int u = 0; u < 4; ++u) {
      int l = lane + u * 64;
      gv[u] = gp[l] + gp[256 + l];
      M = fmaxf(M, gv[u]);
    }
#pragma unroll
    for (int s = 1; s < 64; s <<= 1) M = fmaxf(M, __shfl_xor(M, s));
    float S = 0.f, ev[4];
#pragma unroll
    for (int u = 0; u < 4; ++u) { ev[u] = __expf(gv[u] - M); S += ev[u]; }
#pragma unroll
    for (int s = 1; s < 64; s <<= 1) S += __shfl_xor(S, s);
    float inv = 1.f / S;
#pragma unroll
    for (int u = 0; u < 4; ++u) betas[lane + u * 64] = ev[u] * inv;
  }
  __syncthreads();

  // ---- pass 2: recompute a-tiles, accumulate beta-weighted pooled output ----
  {
    float bl_[4][4];
#pragma unroll
    for (int lf = 0; lf < 4; ++lf)
#pragma unroll
      for (int r = 0; r < 4; ++r)
        bl_[lf][r] = betas[wl3 * 64 + lf * 16 + lg * 4 + r];

    for (int dct = 0; dct < 4; ++dct) {
      f32x4_t accB[4][4];
#pragma unroll
      for (int lf = 0; lf < 4; ++lf)
#pragma unroll
        for (int df = 0; df < 4; ++df) accB[lf][df] = (f32x4_t){0.f, 0.f, 0.f, 0.f};
      run_dct(dct, accB);

      float s1p[4] = {0.f, 0.f, 0.f, 0.f};
      float s2p[4] = {0.f, 0.f, 0.f, 0.f};
#pragma unroll
      for (int lf = 0; lf < 4; ++lf)
#pragma unroll
        for (int r = 0; r < 4; ++r) {
          int l = wl3 * 64 + lf * 16 + lg * 4 + r;
          float bl = bl_[lf][r];
#pragma unroll
          for (int df = 0; df < 4; ++df) {
            int d = dct * 128 + wd * 64 + df * 16 + lq;
            float av = accB[lf][df][r];
            float xv = x[(size_t)l * DD + d];
            s1p[df] += bl * (xv - av);
            s2p[df] += bl * (xv * av);
          }
        }
#pragma unroll
      for (int df = 0; df < 4; ++df) {
        s1p[df] += __shfl_xor(s1p[df], 16);
        s1p[df] += __shfl_xor(s1p[df], 32);
        s2p[df] += __shfl_xor(s2p[df], 16);
        s2p[df] += __shfl_xor(s2p[df], 32);
      }
      if (lg == 0) {
#pragma unroll
        for (int df = 0; df < 4; ++df) {
          int dl = wd * 64 + df * 16 + lq;
          s1dct[wl3 * 128 + dl] = s1p[df];
          s2dct[wl3 * 128 + dl] = s2p[df];
        }
      }
      __syncthreads();
      if (tid < 128) {
        float v1 = s1dct[tid] + s1dct[128 + tid] + s1dct[256 + tid] + s1dct[384 + tid];
        float v2 = s2dct[tid] + s2dct[128 + tid] + s2dct[256 + tid] + s2dct[384 + tid];
        size_t o = (size_t)side * (512u * 1024u) + (size_t)b * 1024u;
        out[o + dct * 128 + tid] = v1;
        out[o + 512 + dct * 128 + tid] = v2;
      }
      // next dct's first __syncthreads() (in run_dct) guards s1dct/s2dct reuse
    }
  }
}

extern "C" void kernel_launch(void* const* d_in, const int* in_sizes, int n_in,
                              void* d_out, int out_size, void* d_ws, size_t ws_size,
                              hipStream_t stream) {
  (void)in_sizes; (void)n_in; (void)out_size; (void)ws_size;
  const float* gi = (const float*)d_in[0];
  const float* gj = (const float*)d_in[1];
  const float* W  = (const float*)d_in[2];
  const float* wv = (const float*)d_in[3];
  float* out = (float*)d_out;
  f16* Wt = (f16*)d_ws;                 // 512x512 f16 = 512 KiB
  f16* slabs = Wt + DD * DD;            // 1024 slabs x 256 KiB (P baked)
  k_prep<<<dim3(64), dim3(256), 0, stream>>>(W, Wt);
  k_main<<<dim3(1024), dim3(512), 0, stream>>>(gi, gj, Wt, wv, slabs, out);
}